// Round 1
// baseline (123750.317 us; speedup 1.0000x reference)
//
#include <hip/hip_runtime.h>
#include <hip/hip_cooperative_groups.h>

namespace cg = cooperative_groups;

#define B_   128
#define T_   512
#define E_   300
#define H_   1024
#define KL_  15
#define G3_  (3*H_)

#define NBLK 256
#define NTHR 512
#define BT_B 64
#define BT_J 8

// Scratch in device globals: no dependence on ws_size.
__device__ __align__(16) float g_h[2][B_][H_];      // main hidden double buffer
__device__ float g_keyxp[KL_][G3_];                 // key input projections
__device__ float g_kh[2][H_];                       // key GRU hidden double buffer
__device__ float g_gate[H_];                        // sigmoid key gate

__device__ __forceinline__ float sigmoidf_(float v) { return 1.0f / (1.0f + expf(-v)); }

__global__ void __launch_bounds__(NTHR, 1) keyed_gru_kernel(
    const int* __restrict__ x, const int* __restrict__ key_ids,
    const float* __restrict__ emb, const float* __restrict__ W_ih,
    const float* __restrict__ W_hh, const float* __restrict__ b_ih,
    const float* __restrict__ b_hh, const float* __restrict__ W_g,
    const float* __restrict__ b_g, float* __restrict__ out)
{
    cg::grid_group grid = cg::this_grid();
    const int tid  = threadIdx.x;
    const int bid  = blockIdx.x;
    const int gtid = bid * NTHR + tid;   // 0 .. 131071 == B_*H_

    // ---------- Phase 0: init h0 / kh0, compute key xproj ----------
    {
        int bb = gtid >> 10, jj = gtid & (H_ - 1);
        g_h[0][bb][jj] = 0.0f;
        if (gtid < H_) g_kh[0][gtid] = 0.0f;
        if (gtid < KL_ * G3_) {
            int s = gtid / G3_, g = gtid - s * G3_;
            const float* e = emb + (size_t)key_ids[s] * E_;
            const float* w = W_ih + (size_t)g * E_;
            float acc = b_ih[g];
            for (int k = 0; k < E_; ++k) acc = fmaf(e[k], w[k], acc);
            g_keyxp[s][g] = acc;
        }
    }
    grid.sync();

    // ---------- Phase 1: key GRU, 15 sequential steps, batch 1 ----------
    // one wave per output channel j (1024 waves of the 2048 in flight)
    const int wid  = gtid >> 6;
    const int lane = tid & 63;
    int cur = 0;
    for (int t = 0; t < KL_; ++t) {
        if (wid < H_) {
            const int j = wid;
            const float* wr = W_hh + (size_t)j * H_;
            const float* wz = W_hh + (size_t)(j + H_) * H_;
            const float* wn = W_hh + (size_t)(j + 2*H_) * H_;
            float ar = 0.f, az = 0.f, an = 0.f;
            for (int k = lane; k < H_; k += 64) {
                float hv = g_kh[cur][k];
                ar = fmaf(hv, wr[k], ar);
                az = fmaf(hv, wz[k], az);
                an = fmaf(hv, wn[k], an);
            }
            #pragma unroll
            for (int off = 32; off > 0; off >>= 1) {
                ar += __shfl_down(ar, off);
                az += __shfl_down(az, off);
                an += __shfl_down(an, off);
            }
            if (lane == 0) {
                float r = sigmoidf_(g_keyxp[t][j] + ar + b_hh[j]);
                float z = sigmoidf_(g_keyxp[t][j + H_] + az + b_hh[j + H_]);
                float n = tanhf(g_keyxp[t][j + 2*H_] + r * (an + b_hh[j + 2*H_]));
                g_kh[cur ^ 1][j] = (1.f - z) * n + z * g_kh[cur][j];
            }
        }
        grid.sync();
        cur ^= 1;
    }

    // ---------- Phase 2: gate = sigmoid(k_h @ W_g.T + b_g) ----------
    if (wid < H_) {
        const int j = wid;
        const float* wg = W_g + (size_t)j * H_;
        float a = 0.f;
        for (int k = lane; k < H_; k += 64) a = fmaf(g_kh[cur][k], wg[k], a);
        #pragma unroll
        for (int off = 32; off > 0; off >>= 1) a += __shfl_down(a, off);
        if (lane == 0) g_gate[j] = sigmoidf_(a + b_g[j]);
    }
    grid.sync();

    // ---------- Phase 3: main recurrence, 512 steps ----------
    // block = (batch tile 64) x (j tile 8); thread = one (b, j)
    const int btile = bid >> 7;          // 0..1
    const int jtile = bid & 127;         // 0..127
    const int bl = tid >> 3;             // 0..63
    const int jl = tid & 7;              // 0..7
    const int b = btile * BT_B + bl;
    const int j = jtile * BT_J + jl;

    const float gate_j = g_gate[j];
    const float br   = b_ih[j]        + b_hh[j];
    const float bz   = b_ih[j + H_]   + b_hh[j + H_];
    const float bhn  = b_hh[j + 2*H_];
    const float bin_ = b_ih[j + 2*H_];
    const float4* wr4  = (const float4*)(W_hh + (size_t)j * H_);
    const float4* wz4  = (const float4*)(W_hh + (size_t)(j + H_) * H_);
    const float4* wn4  = (const float4*)(W_hh + (size_t)(j + 2*H_) * H_);
    const float4* wir4 = (const float4*)(W_ih + (size_t)j * E_);
    const float4* wiz4 = (const float4*)(W_ih + (size_t)(j + H_) * E_);
    const float4* win4 = (const float4*)(W_ih + (size_t)(j + 2*H_) * E_);
    const int* xrow = x + (size_t)b * T_;

    int hb = 0;
    for (int t = 0; t < T_; ++t) {
        const float4* e4 = (const float4*)(emb + (size_t)xrow[t] * E_);  // E_=300 divisible by 4, rows 16B-aligned
        const float4* h4 = (const float4*)(&g_h[hb][b][0]);
        float ar = 0.f, az = 0.f, an = 0.f;
        #pragma unroll 4
        for (int kk = 0; kk < H_/4; ++kk) {
            float4 hv = h4[kk];
            float4 wa = wr4[kk], wb = wz4[kk], wc = wn4[kk];
            ar = fmaf(hv.x, wa.x, fmaf(hv.y, wa.y, fmaf(hv.z, wa.z, fmaf(hv.w, wa.w, ar))));
            az = fmaf(hv.x, wb.x, fmaf(hv.y, wb.y, fmaf(hv.z, wb.z, fmaf(hv.w, wb.w, az))));
            an = fmaf(hv.x, wc.x, fmaf(hv.y, wc.y, fmaf(hv.z, wc.z, fmaf(hv.w, wc.w, an))));
        }
        float xr = 0.f, xz = 0.f, xn = 0.f;
        #pragma unroll 3
        for (int kk = 0; kk < E_/4; ++kk) {
            float4 ev = e4[kk];
            float4 wa = wir4[kk], wb = wiz4[kk], wc = win4[kk];
            xr = fmaf(ev.x, wa.x, fmaf(ev.y, wa.y, fmaf(ev.z, wa.z, fmaf(ev.w, wa.w, xr))));
            xz = fmaf(ev.x, wb.x, fmaf(ev.y, wb.y, fmaf(ev.z, wb.z, fmaf(ev.w, wb.w, xz))));
            xn = fmaf(ev.x, wc.x, fmaf(ev.y, wc.y, fmaf(ev.z, wc.z, fmaf(ev.w, wc.w, xn))));
        }
        float r = sigmoidf_(xr + ar + br);
        float z = sigmoidf_(xz + az + bz);
        float n = tanhf(xn + bin_ + r * (an + bhn));
        float hold = g_h[hb][b][j];
        g_h[hb ^ 1][b][j] = gate_j * ((1.f - z) * n + z * hold);
        grid.sync();
        hb ^= 1;
    }

    out[(size_t)b * H_ + j] = g_h[hb][b][j];
}

extern "C" void kernel_launch(void* const* d_in, const int* in_sizes, int n_in,
                              void* d_out, int out_size, void* d_ws, size_t ws_size,
                              hipStream_t stream) {
    const int*   x       = (const int*)d_in[0];
    const int*   key_ids = (const int*)d_in[1];
    const float* emb     = (const float*)d_in[2];
    const float* W_ih    = (const float*)d_in[3];
    const float* W_hh    = (const float*)d_in[4];
    const float* b_ih    = (const float*)d_in[5];
    const float* b_hh    = (const float*)d_in[6];
    const float* W_g     = (const float*)d_in[7];
    const float* b_g     = (const float*)d_in[8];
    float* out = (float*)d_out;

    void* args[] = {(void*)&x, (void*)&key_ids, (void*)&emb, (void*)&W_ih, (void*)&W_hh,
                    (void*)&b_ih, (void*)&b_hh, (void*)&W_g, (void*)&b_g, (void*)&out};
    hipLaunchCooperativeKernel((const void*)keyed_gru_kernel,
                               dim3(NBLK), dim3(NTHR), args, 0, stream);
}

// Round 5
// 47617.273 us; speedup vs baseline: 2.5989x; 2.5989x over previous
//
#include <hip/hip_runtime.h>
#include <hip/hip_cooperative_groups.h>

namespace cg = cooperative_groups;

#define B_   128
#define T_   512
#define E_   300
#define H_   1024
#define KL_  15
#define G3_  3072

#define NBLK 256
#define NTHR 512
#define GT   (NBLK*NTHR)        // 131072 threads
#define NWAVE_G (GT/64)         // 2048 waves

// Logical K = 544 segs (8 elems each) = 136 k32-tiles = 8 slices x 68 segs (17 tiles)
// regions (logical segs): [0,128) h_hi@Whh_hi | [128,256) h_lo@Whh_hi | [256,384) h_hi@Whh_lo
//   | [384,432) e_hi@Wih_hi | [432,480) e_lo@Wih_hi | [480,528) e_hi@Wih_lo | [528,544) zero
// A-buf col-segs: [0,128) h_hi | [128,256) h_lo | [256,304) e_hi | [304,352) e_lo | [352,368) zero
#define NSEG_A 368
#define KT_    8                // k-slices
#define TPK    17               // k32-tiles per slice
#define SPK    68               // segs per slice
#define NTW    96               // n-tile width

typedef __attribute__((ext_vector_type(8))) short short8;
typedef __attribute__((ext_vector_type(4))) float floatx4;

__device__ __align__(16) unsigned short g_AbufT[NSEG_A][B_][8];  // 753 KB
__device__ float g_hstate[B_][H_];
__device__ float g_Ypart[KT_][B_][G3_];                          // 12.6 MB
__device__ float g_YpartE[KT_][B_][H_];                          // 4.2 MB (n-gate e-partials)
__device__ float g_keyxp[KL_][G3_];
__device__ float g_kh[2][H_];
__device__ float g_gate[H_];

__device__ __forceinline__ float sigf(float v){ return 1.0f/(1.0f+expf(-v)); }
__device__ __forceinline__ unsigned short bfhi(float f){
    unsigned u = __float_as_uint(f);
    return (unsigned short)((u + 0x7FFFu + ((u>>16)&1u)) >> 16);
}
__device__ __forceinline__ float bf2f(unsigned short h){ return __uint_as_float(((unsigned)h)<<16); }

__device__ __forceinline__ int acolseg(int s){   // logical seg -> A-buf col-seg
    if (s < 256) return s;            // h_hi / h_lo
    if (s < 384) return s - 256;      // h_hi again (vs Whh_lo)
    if (s < 480) return s - 128;      // e_hi [384,432)->256..303 ; e_lo [432,480)->304..351
    if (s < 528) return s - 224;      // e_hi again (vs Wih_lo) ->256..303
    return s - 176;                   // zero pad ->352..367
}

#define GLOAD_LDS16(g, l) __builtin_amdgcn_global_load_lds( \
    (const __attribute__((address_space(1))) unsigned int*)(g), \
    (__attribute__((address_space(3))) unsigned int*)(l), 16, 0, 0)

__global__ void __launch_bounds__(NTHR, 1) keyed_gru_kernel(
    const int* __restrict__ x, const int* __restrict__ key_ids,
    const float* __restrict__ emb, const float* __restrict__ W_ih,
    const float* __restrict__ W_hh, const float* __restrict__ b_ih,
    const float* __restrict__ b_hh, const float* __restrict__ W_g,
    const float* __restrict__ b_g, float* __restrict__ out)
{
    cg::grid_group grid = cg::this_grid();
    const int tid  = threadIdx.x;
    const int bid  = blockIdx.x;
    const int gtid = bid * NTHR + tid;

    __shared__ __align__(16) unsigned short Blds[SPK][NTW][8];   // 104448 B
    __shared__ __align__(16) unsigned short Alds[2][4][B_][8];   // 16384 B

    const int kt = bid & 7;         // k-slice 0..7
    const int nt = bid >> 3;        // n-tile 0..31

    // ---------------- Phase 0 ----------------
    for (int idx = gtid; idx < B_*H_; idx += GT)
        ((float*)g_hstate)[idx] = 0.f;
    for (int idx = gtid; idx < 256*B_*8; idx += GT)      // zero h_hi/h_lo col-segs
        ((unsigned short*)g_AbufT)[idx] = 0;
    for (int idx = gtid; idx < 16*B_*8; idx += GT)       // zero pad col-segs [352,368)
        ((unsigned short*)&g_AbufT[352][0][0])[idx] = 0;
    // e-gather+split for t=0
    for (int idx = gtid; idx < B_*384; idx += GT) {
        int b = idx / 384, jj = idx % 384;
        float v = (jj < E_) ? emb[(size_t)x[b*T_ + 0]*E_ + jj] : 0.f;
        unsigned short hi = bfhi(v);
        g_AbufT[256 + (jj>>3)][b][jj&7] = hi;
        g_AbufT[304 + (jj>>3)][b][jj&7] = bfhi(v - bf2f(hi));
    }
    // key xproj (full fp32)
    for (int idx = gtid; idx < KL_*G3_; idx += GT) {
        int s = idx / G3_, g = idx - s*G3_;
        const float* e = emb + (size_t)key_ids[s]*E_;
        const float* w = W_ih + (size_t)g*E_;
        float acc = b_ih[g];
        for (int k = 0; k < E_; ++k) acc = fmaf(e[k], w[k], acc);
        g_keyxp[s][g] = acc;
    }
    if (gtid < H_) g_kh[0][gtid] = 0.f;
    // B-panel build (per block, LDS-resident for whole kernel)
    for (int idx = tid; idx < SPK*NTW; idx += NTHR) {
        int c = idx / SPK, s = idx % SPK;
        int n = nt*NTW + c;
        int sg = kt*SPK + s;
        unsigned short v[8];
        if (sg < 128) {                                   // Whh_hi
            const float* src = W_hh + (size_t)n*H_ + sg*8;
            #pragma unroll
            for (int e2 = 0; e2 < 8; ++e2) v[e2] = bfhi(src[e2]);
        } else if (sg < 256) {                            // Whh_hi (vs h_lo)
            const float* src = W_hh + (size_t)n*H_ + (sg-128)*8;
            #pragma unroll
            for (int e2 = 0; e2 < 8; ++e2) v[e2] = bfhi(src[e2]);
        } else if (sg < 384) {                            // Whh_lo
            const float* src = W_hh + (size_t)n*H_ + (sg-256)*8;
            #pragma unroll
            for (int e2 = 0; e2 < 8; ++e2) { unsigned short hi = bfhi(src[e2]); v[e2] = bfhi(src[e2] - bf2f(hi)); }
        } else if (sg < 432) {                            // Wih_hi (vs e_hi)
            int k0 = (sg-384)*8;
            #pragma unroll
            for (int e2 = 0; e2 < 8; ++e2) { int k = k0+e2; v[e2] = (k < E_) ? bfhi(W_ih[(size_t)n*E_ + k]) : (unsigned short)0; }
        } else if (sg < 480) {                            // Wih_hi (vs e_lo)
            int k0 = (sg-432)*8;
            #pragma unroll
            for (int e2 = 0; e2 < 8; ++e2) { int k = k0+e2; v[e2] = (k < E_) ? bfhi(W_ih[(size_t)n*E_ + k]) : (unsigned short)0; }
        } else if (sg < 528) {                            // Wih_lo (vs e_hi)
            int k0 = (sg-480)*8;
            #pragma unroll
            for (int e2 = 0; e2 < 8; ++e2) {
                int k = k0+e2;
                if (k < E_) { float f = W_ih[(size_t)n*E_ + k]; unsigned short hi = bfhi(f); v[e2] = bfhi(f - bf2f(hi)); }
                else v[e2] = 0;
            }
        } else {                                          // zero pad
            #pragma unroll
            for (int e2 = 0; e2 < 8; ++e2) v[e2] = 0;
        }
        #pragma unroll
        for (int e2 = 0; e2 < 8; ++e2) Blds[s][c][e2] = v[e2];
    }
    grid.sync();

    // ---------------- Phase 1: key GRU (15 steps, fp32) ----------------
    const int wid0 = gtid >> 6;
    const int lane = tid & 63;
    int cur = 0;
    for (int t = 0; t < KL_; ++t) {
        for (int j = wid0; j < H_; j += NWAVE_G) {
            const float* wr = W_hh + (size_t)j * H_;
            const float* wz = W_hh + (size_t)(j + H_) * H_;
            const float* wn = W_hh + (size_t)(j + 2*H_) * H_;
            float ar = 0.f, az = 0.f, an = 0.f;
            for (int k = lane; k < H_; k += 64) {
                float hv = g_kh[cur][k];
                ar = fmaf(hv, wr[k], ar); az = fmaf(hv, wz[k], az); an = fmaf(hv, wn[k], an);
            }
            #pragma unroll
            for (int off = 32; off > 0; off >>= 1) {
                ar += __shfl_down(ar, off); az += __shfl_down(az, off); an += __shfl_down(an, off);
            }
            if (lane == 0) {
                float r = sigf(g_keyxp[t][j] + ar + b_hh[j]);
                float z = sigf(g_keyxp[t][j + H_] + az + b_hh[j + H_]);
                float n = tanhf(g_keyxp[t][j + 2*H_] + r * (an + b_hh[j + 2*H_]));
                g_kh[cur ^ 1][j] = (1.f - z) * n + z * g_kh[cur][j];
            }
        }
        grid.sync();
        cur ^= 1;
    }
    // ---------------- Phase 2: key gate ----------------
    for (int j = wid0; j < H_; j += NWAVE_G) {
        const float* wg = W_g + (size_t)j * H_;
        float a = 0.f;
        for (int k = lane; k < H_; k += 64) a = fmaf(g_kh[cur][k], wg[k], a);
        #pragma unroll
        for (int off = 32; off > 0; off >>= 1) a += __shfl_down(a, off);
        if (lane == 0) g_gate[j] = sigf(a + b_g[j]);
    }
    grid.sync();

    // ---------------- Phase 3: main recurrence ----------------
    const int w  = tid >> 6;          // wave 0..7
    const int ln = tid & 63;
    const int mw = (w >> 1) * 32;     // wave M offset (M32 tiles)
    const int nw = (w & 1) * 48;      // wave N offset (N48 tiles)
    const int fr = ln & 15;
    const int fq = ln >> 4;

    for (int t = 0; t < T_; ++t) {
        floatx4 accH[2][3], accE[2][3];
        #pragma unroll
        for (int tm = 0; tm < 2; ++tm)
            #pragma unroll
            for (int tn = 0; tn < 3; ++tn) {
                accH[tm][tn] = (floatx4){0.f,0.f,0.f,0.f};
                accE[tm][tn] = (floatx4){0.f,0.f,0.f,0.f};
            }

        // stage chunk 0
        {
            int segbase = kt*SPK;
            int s = tid >> 7, r = tid & 127;
            int acs = acolseg(segbase + s);
            GLOAD_LDS16((const char*)&g_AbufT[acs][r][0], (char*)&Alds[0][0][0][0] + tid*16);
        }
        for (int ct = 0; ct < TPK; ++ct) {
            __syncthreads();
            if (ct < TPK-1) {
                int segbase = kt*SPK + (ct+1)*4;
                int buf = (ct+1) & 1;
                int s = tid >> 7, r = tid & 127;
                int acs = acolseg(segbase + s);
                GLOAD_LDS16((const char*)&g_AbufT[acs][r][0], (char*)&Alds[buf][0][0][0] + tid*16);
            }
            int buf = ct & 1;
            short8 af[2], bf[3];
            #pragma unroll
            for (int tm = 0; tm < 2; ++tm)
                af[tm] = *(const short8*)&Alds[buf][fq][mw + tm*16 + fr][0];
            #pragma unroll
            for (int tn = 0; tn < 3; ++tn)
                bf[tn] = *(const short8*)&Blds[ct*4 + fq][nw + tn*16 + fr][0];
            bool ish = (kt*SPK + ct*4) < 384;     // wave-uniform: h-region vs e-region tile
            if (ish) {
                #pragma unroll
                for (int tm = 0; tm < 2; ++tm)
                    #pragma unroll
                    for (int tn = 0; tn < 3; ++tn)
                        accH[tm][tn] = __builtin_amdgcn_mfma_f32_16x16x32_bf16(af[tm], bf[tn], accH[tm][tn], 0, 0, 0);
            } else {
                #pragma unroll
                for (int tm = 0; tm < 2; ++tm)
                    #pragma unroll
                    for (int tn = 0; tn < 3; ++tn)
                        accE[tm][tn] = __builtin_amdgcn_mfma_f32_16x16x32_bf16(af[tm], bf[tn], accE[tm][tn], 0, 0, 0);
            }
        }
        // write C partials: r/z cols get accH+accE; n cols (>=2048) keep them split
        #pragma unroll
        for (int tm = 0; tm < 2; ++tm) {
            #pragma unroll
            for (int tn = 0; tn < 3; ++tn) {
                int colbase = nt*NTW + nw + tn*16;
                int ncol = colbase + fr;
                bool isn = colbase >= 2048;       // wave-uniform (16-col fragment aligned to 2048)
                #pragma unroll
                for (int reg = 0; reg < 4; ++reg) {
                    int brow = mw + tm*16 + fq*4 + reg;
                    if (!isn) {
                        g_Ypart[kt][brow][ncol] = accH[tm][tn][reg] + accE[tm][tn][reg];
                    } else {
                        g_Ypart[kt][brow][ncol] = accH[tm][tn][reg];
                        g_YpartE[kt][brow][ncol - 2048] = accE[tm][tn][reg];
                    }
                }
            }
        }
        grid.sync();

        // epilogue: gates + h update + split-bf16 write (1 element/thread)
        {
            int idx = gtid;            // GT == B_*H_
            int b = idx >> 10, j = idx & (H_-1);
            float sr = 0.f, sz = 0.f, hn = 0.f, xn = 0.f;
            #pragma unroll
            for (int p = 0; p < KT_; ++p) {
                sr += g_Ypart[p][b][j];
                sz += g_Ypart[p][b][H_ + j];
                hn += g_Ypart[p][b][2*H_ + j];
                xn += g_YpartE[p][b][j];
            }
            float r = sigf(sr + b_ih[j] + b_hh[j]);
            float z = sigf(sz + b_ih[H_+j] + b_hh[H_+j]);
            float n = tanhf(xn + b_ih[2*H_+j] + r * (hn + b_hh[2*H_+j]));
            float hold = g_hstate[b][j];
            float hnew = g_gate[j] * ((1.f - z) * n + z * hold);
            g_hstate[b][j] = hnew;
            unsigned short hi = bfhi(hnew);
            g_AbufT[j>>3][b][j&7] = hi;
            g_AbufT[128 + (j>>3)][b][j&7] = bfhi(hnew - bf2f(hi));
            if (t == T_-1) out[(size_t)b*H_ + j] = hnew;
        }
        // gather+split e for next step
        if (t + 1 < T_) {
            for (int idx = gtid; idx < B_*384; idx += GT) {
                int b = idx / 384, jj = idx % 384;
                float v = (jj < E_) ? emb[(size_t)x[b*T_ + t + 1]*E_ + jj] : 0.f;
                unsigned short hi = bfhi(v);
                g_AbufT[256 + (jj>>3)][b][jj&7] = hi;
                g_AbufT[304 + (jj>>3)][b][jj&7] = bfhi(v - bf2f(hi));
            }
        }
        grid.sync();
    }
}

extern "C" void kernel_launch(void* const* d_in, const int* in_sizes, int n_in,
                              void* d_out, int out_size, void* d_ws, size_t ws_size,
                              hipStream_t stream) {
    const int*   x       = (const int*)d_in[0];
    const int*   key_ids = (const int*)d_in[1];
    const float* emb     = (const float*)d_in[2];
    const float* W_ih    = (const float*)d_in[3];
    const float* W_hh    = (const float*)d_in[4];
    const float* b_ih    = (const float*)d_in[5];
    const float* b_hh    = (const float*)d_in[6];
    const float* W_g     = (const float*)d_in[7];
    const float* b_g     = (const float*)d_in[8];
    float* out = (float*)d_out;

    void* args[] = {(void*)&x, (void*)&key_ids, (void*)&emb, (void*)&W_ih, (void*)&W_hh,
                    (void*)&b_ih, (void*)&b_hh, (void*)&W_g, (void*)&b_g, (void*)&out};
    hipLaunchCooperativeKernel((const void*)keyed_gru_kernel,
                               dim3(NBLK), dim3(NTHR), args, 0, stream);
}

// Round 6
// 25844.955 us; speedup vs baseline: 4.7882x; 1.8424x over previous
//
#include <hip/hip_runtime.h>

#define B_   128
#define T_   512
#define E_   300
#define H_   1024
#define KL_  15
#define G3_  3072

#define NBLK 256
#define NTHR 512
#define GT   (NBLK*NTHR)        // 131072 threads
#define NWAVE_G (GT/64)         // 2048 waves

// Logical K = 544 segs (8 elems each) = 136 k32-tiles = 8 slices x 68 segs (17 tiles)
// regions (logical segs): [0,128) h_hi@Whh_hi | [128,256) h_lo@Whh_hi | [256,384) h_hi@Whh_lo
//   | [384,432) e_hi@Wih_hi | [432,480) e_lo@Wih_hi | [480,528) e_hi@Wih_lo | [528,544) zero
// A-buf col-segs: [0,128) h_hi | [128,256) h_lo | [256,304) e_hi | [304,352) e_lo | [352,368) zero
#define NSEG_A 368
#define KT_    8                // k-slices
#define TPK    17               // k32-tiles per slice
#define SPK    68               // segs per slice
#define NTW    96               // n-tile width

typedef __attribute__((ext_vector_type(8))) short short8;
typedef __attribute__((ext_vector_type(4))) float floatx4;

__device__ __align__(16) unsigned short g_AbufT[NSEG_A][B_][8];  // 753 KB
__device__ float g_hstate[B_][H_];
__device__ float g_Ypart[KT_][B_][G3_];                          // 12.6 MB
__device__ float g_YpartE[KT_][B_][H_];                          // 4.2 MB (n-gate e-partials)
__device__ float g_keyxp[KL_][G3_];
__device__ float g_kh[2][H_];
__device__ float g_gate[H_];

// ---- custom grid barrier state (persists across launches; generation-based,
// never reset -> safe under graph replay; zero-init at module load) ----
__device__ unsigned g_abar[NBLK * 32];   // one slot per block, 128B-spaced
__device__ unsigned g_gen;

__device__ __forceinline__ void gbar(unsigned step) {
    const int tid = threadIdx.x, bid = blockIdx.x;
    __syncthreads();   // all threads' prior global writes retired to L2 (vmcnt drain)
    if (tid == 0)      // RELEASE: writeback L2 so remote XCDs can see our writes
        __hip_atomic_store(&g_abar[bid * 32], step, __ATOMIC_RELEASE, __HIP_MEMORY_SCOPE_AGENT);
    if (bid == 0) {
        if (tid < NBLK) {
            while (__hip_atomic_load(&g_abar[tid * 32], __ATOMIC_RELAXED, __HIP_MEMORY_SCOPE_AGENT) < step)
                __builtin_amdgcn_s_sleep(8);
        }
        __syncthreads();
        if (tid == 0)
            __hip_atomic_store(&g_gen, step, __ATOMIC_RELEASE, __HIP_MEMORY_SCOPE_AGENT);
    } else {
        if (tid == 0) {
            while (__hip_atomic_load(&g_gen, __ATOMIC_RELAXED, __HIP_MEMORY_SCOPE_AGENT) < step)
                __builtin_amdgcn_s_sleep(8);
        }
    }
    if (tid == 0)      // ACQUIRE: invalidate L2 so we read remote writes fresh
        (void)__hip_atomic_load(&g_gen, __ATOMIC_ACQUIRE, __HIP_MEMORY_SCOPE_AGENT);
    __syncthreads();
}

__device__ __forceinline__ float sigf(float v){ return 1.0f/(1.0f+expf(-v)); }
__device__ __forceinline__ unsigned short bfhi(float f){
    unsigned u = __float_as_uint(f);
    return (unsigned short)((u + 0x7FFFu + ((u>>16)&1u)) >> 16);
}
__device__ __forceinline__ float bf2f(unsigned short h){ return __uint_as_float(((unsigned)h)<<16); }

__device__ __forceinline__ int acolseg(int s){   // logical seg -> A-buf col-seg
    if (s < 256) return s;            // h_hi / h_lo
    if (s < 384) return s - 256;      // h_hi again (vs Whh_lo)
    if (s < 480) return s - 128;      // e_hi [384,432)->256..303 ; e_lo [432,480)->304..351
    if (s < 528) return s - 224;      // e_hi again (vs Wih_lo) ->256..303
    return s - 176;                   // zero pad ->352..367
}

#define GLOAD_LDS16(g, l) __builtin_amdgcn_global_load_lds( \
    (const __attribute__((address_space(1))) unsigned int*)(g), \
    (__attribute__((address_space(3))) unsigned int*)(l), 16, 0, 0)

__global__ void __launch_bounds__(NTHR, 1) keyed_gru_kernel(
    const int* __restrict__ x, const int* __restrict__ key_ids,
    const float* __restrict__ emb, const float* __restrict__ W_ih,
    const float* __restrict__ W_hh, const float* __restrict__ b_ih,
    const float* __restrict__ b_hh, const float* __restrict__ W_g,
    const float* __restrict__ b_g, float* __restrict__ out)
{
    const int tid  = threadIdx.x;
    const int bid  = blockIdx.x;
    const int gtid = bid * NTHR + tid;

    // barrier generation base: stable & uniform at entry (nobody stores until first gbar)
    unsigned bstep = __hip_atomic_load(&g_gen, __ATOMIC_RELAXED, __HIP_MEMORY_SCOPE_AGENT);

    __shared__ __align__(16) unsigned short Blds[SPK][NTW][8];   // 104448 B
    __shared__ __align__(16) unsigned short Alds[2][4][B_][8];   // 16384 B

    const int kt = bid & 7;         // k-slice 0..7
    const int nt = bid >> 3;        // n-tile 0..31

    // ---------------- Phase 0 ----------------
    for (int idx = gtid; idx < B_*H_; idx += GT)
        ((float*)g_hstate)[idx] = 0.f;
    for (int idx = gtid; idx < 256*B_*8; idx += GT)      // zero h_hi/h_lo col-segs
        ((unsigned short*)g_AbufT)[idx] = 0;
    for (int idx = gtid; idx < 16*B_*8; idx += GT)       // zero pad col-segs [352,368)
        ((unsigned short*)&g_AbufT[352][0][0])[idx] = 0;
    // e-gather+split for t=0
    for (int idx = gtid; idx < B_*384; idx += GT) {
        int b = idx / 384, jj = idx % 384;
        float v = (jj < E_) ? emb[(size_t)x[b*T_ + 0]*E_ + jj] : 0.f;
        unsigned short hi = bfhi(v);
        g_AbufT[256 + (jj>>3)][b][jj&7] = hi;
        g_AbufT[304 + (jj>>3)][b][jj&7] = bfhi(v - bf2f(hi));
    }
    // key xproj (full fp32)
    for (int idx = gtid; idx < KL_*G3_; idx += GT) {
        int s = idx / G3_, g = idx - s*G3_;
        const float* e = emb + (size_t)key_ids[s]*E_;
        const float* w = W_ih + (size_t)g*E_;
        float acc = b_ih[g];
        for (int k = 0; k < E_; ++k) acc = fmaf(e[k], w[k], acc);
        g_keyxp[s][g] = acc;
    }
    if (gtid < H_) g_kh[0][gtid] = 0.f;
    // B-panel build (per block, LDS-resident for whole kernel)
    for (int idx = tid; idx < SPK*NTW; idx += NTHR) {
        int c = idx / SPK, s = idx % SPK;
        int n = nt*NTW + c;
        int sg = kt*SPK + s;
        unsigned short v[8];
        if (sg < 128) {                                   // Whh_hi
            const float* src = W_hh + (size_t)n*H_ + sg*8;
            #pragma unroll
            for (int e2 = 0; e2 < 8; ++e2) v[e2] = bfhi(src[e2]);
        } else if (sg < 256) {                            // Whh_hi (vs h_lo)
            const float* src = W_hh + (size_t)n*H_ + (sg-128)*8;
            #pragma unroll
            for (int e2 = 0; e2 < 8; ++e2) v[e2] = bfhi(src[e2]);
        } else if (sg < 384) {                            // Whh_lo
            const float* src = W_hh + (size_t)n*H_ + (sg-256)*8;
            #pragma unroll
            for (int e2 = 0; e2 < 8; ++e2) { unsigned short hi = bfhi(src[e2]); v[e2] = bfhi(src[e2] - bf2f(hi)); }
        } else if (sg < 432) {                            // Wih_hi (vs e_hi)
            int k0 = (sg-384)*8;
            #pragma unroll
            for (int e2 = 0; e2 < 8; ++e2) { int k = k0+e2; v[e2] = (k < E_) ? bfhi(W_ih[(size_t)n*E_ + k]) : (unsigned short)0; }
        } else if (sg < 480) {                            // Wih_hi (vs e_lo)
            int k0 = (sg-432)*8;
            #pragma unroll
            for (int e2 = 0; e2 < 8; ++e2) { int k = k0+e2; v[e2] = (k < E_) ? bfhi(W_ih[(size_t)n*E_ + k]) : (unsigned short)0; }
        } else if (sg < 528) {                            // Wih_lo (vs e_hi)
            int k0 = (sg-480)*8;
            #pragma unroll
            for (int e2 = 0; e2 < 8; ++e2) {
                int k = k0+e2;
                if (k < E_) { float f = W_ih[(size_t)n*E_ + k]; unsigned short hi = bfhi(f); v[e2] = bfhi(f - bf2f(hi)); }
                else v[e2] = 0;
            }
        } else {                                          // zero pad
            #pragma unroll
            for (int e2 = 0; e2 < 8; ++e2) v[e2] = 0;
        }
        #pragma unroll
        for (int e2 = 0; e2 < 8; ++e2) Blds[s][c][e2] = v[e2];
    }
    gbar(++bstep);

    // ---------------- Phase 1: key GRU (15 steps, fp32) ----------------
    const int wid0 = gtid >> 6;
    const int lane = tid & 63;
    int cur = 0;
    for (int t = 0; t < KL_; ++t) {
        for (int j = wid0; j < H_; j += NWAVE_G) {
            const float* wr = W_hh + (size_t)j * H_;
            const float* wz = W_hh + (size_t)(j + H_) * H_;
            const float* wn = W_hh + (size_t)(j + 2*H_) * H_;
            float ar = 0.f, az = 0.f, an = 0.f;
            for (int k = lane; k < H_; k += 64) {
                float hv = g_kh[cur][k];
                ar = fmaf(hv, wr[k], ar); az = fmaf(hv, wz[k], az); an = fmaf(hv, wn[k], an);
            }
            #pragma unroll
            for (int off = 32; off > 0; off >>= 1) {
                ar += __shfl_down(ar, off); az += __shfl_down(az, off); an += __shfl_down(an, off);
            }
            if (lane == 0) {
                float r = sigf(g_keyxp[t][j] + ar + b_hh[j]);
                float z = sigf(g_keyxp[t][j + H_] + az + b_hh[j + H_]);
                float n = tanhf(g_keyxp[t][j + 2*H_] + r * (an + b_hh[j + 2*H_]));
                g_kh[cur ^ 1][j] = (1.f - z) * n + z * g_kh[cur][j];
            }
        }
        gbar(++bstep);
        cur ^= 1;
    }
    // ---------------- Phase 2: key gate ----------------
    for (int j = wid0; j < H_; j += NWAVE_G) {
        const float* wg = W_g + (size_t)j * H_;
        float a = 0.f;
        for (int k = lane; k < H_; k += 64) a = fmaf(g_kh[cur][k], wg[k], a);
        #pragma unroll
        for (int off = 32; off > 0; off >>= 1) a += __shfl_down(a, off);
        if (lane == 0) g_gate[j] = sigf(a + b_g[j]);
    }
    gbar(++bstep);

    // ---------------- Phase 3: main recurrence ----------------
    const int w  = tid >> 6;          // wave 0..7
    const int ln = tid & 63;
    const int mw = (w >> 1) * 32;     // wave M offset (M32 tiles)
    const int nw = (w & 1) * 48;      // wave N offset (N48 tiles)
    const int fr = ln & 15;
    const int fq = ln >> 4;

    for (int t = 0; t < T_; ++t) {
        floatx4 accH[2][3], accE[2][3];
        #pragma unroll
        for (int tm = 0; tm < 2; ++tm)
            #pragma unroll
            for (int tn = 0; tn < 3; ++tn) {
                accH[tm][tn] = (floatx4){0.f,0.f,0.f,0.f};
                accE[tm][tn] = (floatx4){0.f,0.f,0.f,0.f};
            }

        // stage chunk 0
        {
            int segbase = kt*SPK;
            int s = tid >> 7, r = tid & 127;
            int acs = acolseg(segbase + s);
            GLOAD_LDS16((const char*)&g_AbufT[acs][r][0], (char*)&Alds[0][0][0][0] + tid*16);
        }
        for (int ct = 0; ct < TPK; ++ct) {
            __syncthreads();
            if (ct < TPK-1) {
                int segbase = kt*SPK + (ct+1)*4;
                int buf = (ct+1) & 1;
                int s = tid >> 7, r = tid & 127;
                int acs = acolseg(segbase + s);
                GLOAD_LDS16((const char*)&g_AbufT[acs][r][0], (char*)&Alds[buf][0][0][0] + tid*16);
            }
            int buf = ct & 1;
            short8 af[2], bf[3];
            #pragma unroll
            for (int tm = 0; tm < 2; ++tm)
                af[tm] = *(const short8*)&Alds[buf][fq][mw + tm*16 + fr][0];
            #pragma unroll
            for (int tn = 0; tn < 3; ++tn)
                bf[tn] = *(const short8*)&Blds[ct*4 + fq][nw + tn*16 + fr][0];
            bool ish = (kt*SPK + ct*4) < 384;     // wave-uniform: h-region vs e-region tile
            if (ish) {
                #pragma unroll
                for (int tm = 0; tm < 2; ++tm)
                    #pragma unroll
                    for (int tn = 0; tn < 3; ++tn)
                        accH[tm][tn] = __builtin_amdgcn_mfma_f32_16x16x32_bf16(af[tm], bf[tn], accH[tm][tn], 0, 0, 0);
            } else {
                #pragma unroll
                for (int tm = 0; tm < 2; ++tm)
                    #pragma unroll
                    for (int tn = 0; tn < 3; ++tn)
                        accE[tm][tn] = __builtin_amdgcn_mfma_f32_16x16x32_bf16(af[tm], bf[tn], accE[tm][tn], 0, 0, 0);
            }
        }
        // write C partials: r/z cols get accH+accE; n cols (>=2048) keep them split
        #pragma unroll
        for (int tm = 0; tm < 2; ++tm) {
            #pragma unroll
            for (int tn = 0; tn < 3; ++tn) {
                int colbase = nt*NTW + nw + tn*16;
                int ncol = colbase + fr;
                bool isn = colbase >= 2048;       // wave-uniform (16-col fragment aligned to 2048)
                #pragma unroll
                for (int reg = 0; reg < 4; ++reg) {
                    int brow = mw + tm*16 + fq*4 + reg;
                    if (!isn) {
                        g_Ypart[kt][brow][ncol] = accH[tm][tn][reg] + accE[tm][tn][reg];
                    } else {
                        g_Ypart[kt][brow][ncol] = accH[tm][tn][reg];
                        g_YpartE[kt][brow][ncol - 2048] = accE[tm][tn][reg];
                    }
                }
            }
        }
        gbar(++bstep);

        // epilogue: gates + h update + split-bf16 write (1 element/thread)
        {
            int idx = gtid;            // GT == B_*H_
            int b = idx >> 10, j = idx & (H_-1);
            float sr = 0.f, sz = 0.f, hn = 0.f, xn = 0.f;
            #pragma unroll
            for (int p = 0; p < KT_; ++p) {
                sr += g_Ypart[p][b][j];
                sz += g_Ypart[p][b][H_ + j];
                hn += g_Ypart[p][b][2*H_ + j];
                xn += g_YpartE[p][b][j];
            }
            float r = sigf(sr + b_ih[j] + b_hh[j]);
            float z = sigf(sz + b_ih[H_+j] + b_hh[H_+j]);
            float n = tanhf(xn + b_ih[2*H_+j] + r * (hn + b_hh[2*H_+j]));
            float hold = g_hstate[b][j];
            float hnew = g_gate[j] * ((1.f - z) * n + z * hold);
            g_hstate[b][j] = hnew;
            unsigned short hi = bfhi(hnew);
            g_AbufT[j>>3][b][j&7] = hi;
            g_AbufT[128 + (j>>3)][b][j&7] = bfhi(hnew - bf2f(hi));
            if (t == T_-1) out[(size_t)b*H_ + j] = hnew;
        }
        // gather+split e for next step
        if (t + 1 < T_) {
            for (int idx = gtid; idx < B_*384; idx += GT) {
                int b = idx / 384, jj = idx % 384;
                float v = (jj < E_) ? emb[(size_t)x[b*T_ + t + 1]*E_ + jj] : 0.f;
                unsigned short hi = bfhi(v);
                g_AbufT[256 + (jj>>3)][b][jj&7] = hi;
                g_AbufT[304 + (jj>>3)][b][jj&7] = bfhi(v - bf2f(hi));
            }
        }
        gbar(++bstep);
    }
}

extern "C" void kernel_launch(void* const* d_in, const int* in_sizes, int n_in,
                              void* d_out, int out_size, void* d_ws, size_t ws_size,
                              hipStream_t stream) {
    const int*   x       = (const int*)d_in[0];
    const int*   key_ids = (const int*)d_in[1];
    const float* emb     = (const float*)d_in[2];
    const float* W_ih    = (const float*)d_in[3];
    const float* W_hh    = (const float*)d_in[4];
    const float* b_ih    = (const float*)d_in[5];
    const float* b_hh    = (const float*)d_in[6];
    const float* W_g     = (const float*)d_in[7];
    const float* b_g     = (const float*)d_in[8];
    float* out = (float*)d_out;

    void* args[] = {(void*)&x, (void*)&key_ids, (void*)&emb, (void*)&W_ih, (void*)&W_hh,
                    (void*)&b_ih, (void*)&b_hh, (void*)&W_g, (void*)&b_g, (void*)&out};
    hipLaunchCooperativeKernel((const void*)keyed_gru_kernel,
                               dim3(NBLK), dim3(NTHR), args, 0, stream);
}

// Round 7
// 18900.006 us; speedup vs baseline: 6.5476x; 1.3675x over previous
//
#include <hip/hip_runtime.h>

#define B_   128
#define T_   512
#define E_   300
#define H_   1024
#define KL_  15
#define G3_  3072

#define NBLK 256
#define NTHR 512
#define GT   (NBLK*NTHR)        // 131072 threads
#define NWAVE_G (GT/64)

// A-buf col-seg regions (per parity): [0,128) h_hi | [128,256) h_lo | [256,304) e_hi | [304,352) e_lo
#define ASEG 352
#define NR   44                 // staging rounds of 8 segs (16KB/block, 2KB/wave)

typedef __attribute__((ext_vector_type(8))) short short8;
typedef __attribute__((ext_vector_type(4))) float floatx4;

__device__ __align__(16) unsigned short g_Abuf[2][ASEG][B_][8];  // 2 x 704KB, parity-double-buffered
__device__ float g_keyxp[KL_][G3_];
__device__ float g_kh[2][H_];
__device__ float g_gate[H_];

// ---- custom grid barrier (proven in R6): generation-based, persists across launches ----
__device__ unsigned g_abar[NBLK * 32];
__device__ unsigned g_gen;

__device__ __forceinline__ void gbar(unsigned step) {
    const int tid = threadIdx.x, bid = blockIdx.x;
    __syncthreads();
    if (tid == 0)
        __hip_atomic_store(&g_abar[bid * 32], step, __ATOMIC_RELEASE, __HIP_MEMORY_SCOPE_AGENT);
    if (bid == 0) {
        if (tid < NBLK) {
            while (__hip_atomic_load(&g_abar[tid * 32], __ATOMIC_RELAXED, __HIP_MEMORY_SCOPE_AGENT) < step)
                __builtin_amdgcn_s_sleep(8);
        }
        __syncthreads();
        if (tid == 0)
            __hip_atomic_store(&g_gen, step, __ATOMIC_RELEASE, __HIP_MEMORY_SCOPE_AGENT);
    } else {
        if (tid == 0) {
            while (__hip_atomic_load(&g_gen, __ATOMIC_RELAXED, __HIP_MEMORY_SCOPE_AGENT) < step)
                __builtin_amdgcn_s_sleep(8);
        }
    }
    if (tid == 0)
        (void)__hip_atomic_load(&g_gen, __ATOMIC_ACQUIRE, __HIP_MEMORY_SCOPE_AGENT);
    __syncthreads();
}

__device__ __forceinline__ float sigf(float v){ return 1.0f/(1.0f+expf(-v)); }
__device__ __forceinline__ unsigned short bfhi(float f){
    unsigned u = __float_as_uint(f);
    return (unsigned short)((u + 0x7FFFu + ((u>>16)&1u)) >> 16);
}
__device__ __forceinline__ float bf2f(unsigned short h){ return __uint_as_float(((unsigned)h)<<16); }

#define GLOAD_LDS16(g, l) __builtin_amdgcn_global_load_lds( \
    (const __attribute__((address_space(1))) unsigned int*)(g), \
    (__attribute__((address_space(3))) unsigned int*)(l), 16, 0, 0)

__global__ void __launch_bounds__(NTHR, 1) keyed_gru_kernel(
    const int* __restrict__ x, const int* __restrict__ key_ids,
    const float* __restrict__ emb, const float* __restrict__ W_ih,
    const float* __restrict__ W_hh, const float* __restrict__ b_ih,
    const float* __restrict__ b_hh, const float* __restrict__ W_g,
    const float* __restrict__ b_g, float* __restrict__ out)
{
    const int tid  = threadIdx.x;
    const int bid  = blockIdx.x;
    const int gtid = bid * NTHR + tid;

    unsigned bstep = __hip_atomic_load(&g_gen, __ATOMIC_RELAXED, __HIP_MEMORY_SCOPE_AGENT);

    // LDS: 90112 + 65536 + 2048 + 64 + 16 = 157776 B  (fits 160KB, 1 block/CU)
    __shared__ __align__(16) unsigned short Blds[ASEG][16][8];      // weight panel, resident all steps
    __shared__ __align__(16) unsigned short Aring[4][8][8][16][8];  // [slot][wave][seg][rowl][8]
    __shared__ float hloc[B_][4];
    __shared__ float lbias[4][4];
    __shared__ float lgate[4];

    const int j0 = bid * 4;       // block's 4 h-channels

    // ---------------- Phase 0 ----------------
    for (int idx = gtid; idx < 2*ASEG*B_*8; idx += GT)
        ((unsigned short*)g_Abuf)[idx] = 0;
    // e-gather+split for t=0 into parity 0
    for (int idx = gtid; idx < B_*384; idx += GT) {
        int b = idx / 384, jj = idx % 384;
        float v = (jj < E_) ? emb[(size_t)x[b*T_ + 0]*E_ + jj] : 0.f;
        unsigned short hi = bfhi(v);
        g_Abuf[0][256 + (jj>>3)][b][jj&7] = hi;
        g_Abuf[0][304 + (jj>>3)][b][jj&7] = bfhi(v - bf2f(hi));
    }
    // key xproj (full fp32)
    for (int idx = gtid; idx < KL_*G3_; idx += GT) {
        int s = idx / G3_, g = idx - s*G3_;
        const float* e = emb + (size_t)key_ids[s]*E_;
        const float* wv = W_ih + (size_t)g*E_;
        float acc = b_ih[g];
        for (int k = 0; k < E_; ++k) acc = fmaf(e[k], wv[k], acc);
        g_keyxp[s][g] = acc;
    }
    if (gtid < H_) g_kh[0][gtid] = 0.f;
    // B-panel: block's 12 weight rows (+4 zero pad cols), full split-K, LDS-resident forever
    for (int idx = tid; idx < ASEG*16; idx += NTHR) {
        int seg = idx >> 4, c = idx & 15;
        unsigned short v[8];
        if (c >= 12) {
            #pragma unroll
            for (int e2 = 0; e2 < 8; ++e2) v[e2] = 0;
        } else {
            int wr = (c < 4) ? (j0 + c) : (c < 8) ? (H_ + j0 + c - 4) : (2*H_ + j0 + c - 8);
            if (seg < 128) {                              // Whh_hi
                const float* src = W_hh + (size_t)wr*H_ + seg*8;
                #pragma unroll
                for (int e2 = 0; e2 < 8; ++e2) v[e2] = bfhi(src[e2]);
            } else if (seg < 256) {                       // Whh_lo
                const float* src = W_hh + (size_t)wr*H_ + (seg-128)*8;
                #pragma unroll
                for (int e2 = 0; e2 < 8; ++e2) { unsigned short hi = bfhi(src[e2]); v[e2] = bfhi(src[e2] - bf2f(hi)); }
            } else if (seg < 304) {                       // Wih_hi (k padded 300->384)
                int k0 = (seg-256)*8;
                #pragma unroll
                for (int e2 = 0; e2 < 8; ++e2) { int k = k0+e2; v[e2] = (k < E_) ? bfhi(W_ih[(size_t)wr*E_ + k]) : (unsigned short)0; }
            } else {                                      // Wih_lo
                int k0 = (seg-304)*8;
                #pragma unroll
                for (int e2 = 0; e2 < 8; ++e2) {
                    int k = k0+e2;
                    if (k < E_) { float f = W_ih[(size_t)wr*E_ + k]; unsigned short hi = bfhi(f); v[e2] = bfhi(f - bf2f(hi)); }
                    else v[e2] = 0;
                }
            }
        }
        #pragma unroll
        for (int e2 = 0; e2 < 8; ++e2) Blds[seg][c][e2] = v[e2];
    }
    hloc[tid >> 2][tid & 3] = 0.f;
    gbar(++bstep);

    // ---------------- Phase 1: key GRU (15 steps, fp32) ----------------
    const int wid0 = gtid >> 6;
    const int lane = tid & 63;
    int cur = 0;
    for (int t = 0; t < KL_; ++t) {
        for (int j = wid0; j < H_; j += NWAVE_G) {
            const float* wr = W_hh + (size_t)j * H_;
            const float* wz = W_hh + (size_t)(j + H_) * H_;
            const float* wn = W_hh + (size_t)(j + 2*H_) * H_;
            float ar = 0.f, az = 0.f, an = 0.f;
            for (int k = lane; k < H_; k += 64) {
                float hv = g_kh[cur][k];
                ar = fmaf(hv, wr[k], ar); az = fmaf(hv, wz[k], az); an = fmaf(hv, wn[k], an);
            }
            #pragma unroll
            for (int off = 32; off > 0; off >>= 1) {
                ar += __shfl_down(ar, off); az += __shfl_down(az, off); an += __shfl_down(an, off);
            }
            if (lane == 0) {
                float r = sigf(g_keyxp[t][j] + ar + b_hh[j]);
                float z = sigf(g_keyxp[t][j + H_] + az + b_hh[j + H_]);
                float n = tanhf(g_keyxp[t][j + 2*H_] + r * (an + b_hh[j + 2*H_]));
                g_kh[cur ^ 1][j] = (1.f - z) * n + z * g_kh[cur][j];
            }
        }
        gbar(++bstep);
        cur ^= 1;
    }
    // ---------------- Phase 2: key gate ----------------
    for (int j = wid0; j < H_; j += NWAVE_G) {
        const float* wg = W_g + (size_t)j * H_;
        float a = 0.f;
        for (int k = lane; k < H_; k += 64) a = fmaf(g_kh[cur][k], wg[k], a);
        #pragma unroll
        for (int off = 32; off > 0; off >>= 1) a += __shfl_down(a, off);
        if (lane == 0) g_gate[j] = sigf(a + b_g[j]);
    }
    gbar(++bstep);

    if (tid < 4) {
        int j = j0 + tid;
        lgate[tid]    = g_gate[j];
        lbias[tid][0] = b_ih[j] + b_hh[j];
        lbias[tid][1] = b_ih[H_+j] + b_hh[H_+j];
        lbias[tid][2] = b_hh[2*H_+j];
        lbias[tid][3] = b_ih[2*H_+j];
    }
    __syncthreads();

    // ---------------- Phase 3: main recurrence ----------------
    const int w  = tid >> 6;        // wave 0..7 owns batch rows [16w,16w+16)
    const int ln = tid & 63;
    const int mw = w * 16;
    const int fr = ln & 15;
    const int fq = ln >> 4;

    for (int t = 0; t < T_; ++t) {
        const int par = t & 1;
        const unsigned short* Ab = &g_Abuf[par][0][0][0];

        floatx4 aH0 = {0,0,0,0}, aH1 = {0,0,0,0}, aE0 = {0,0,0,0}, aE1 = {0,0,0,0};

        // prologue: prefetch rounds 0,1 (per-wave private: own 16 rows only)
        #pragma unroll
        for (int pr = 0; pr < 2; ++pr) {
            GLOAD_LDS16(Ab + ((size_t)((pr*8     + (ln>>4))*128 + mw + (ln&15)))*8, &Aring[pr][w][0][0][0]);
            GLOAD_LDS16(Ab + ((size_t)((pr*8 + 4 + (ln>>4))*128 + mw + (ln&15)))*8, &Aring[pr][w][4][0][0]);
        }

        for (int r = 0; r < NR; ++r) {
            if (r < NR-2) {
                const int rr = r + 2, sl2 = rr & 3;
                GLOAD_LDS16(Ab + ((size_t)((rr*8     + (ln>>4))*128 + mw + (ln&15)))*8, &Aring[sl2][w][0][0][0]);
                GLOAD_LDS16(Ab + ((size_t)((rr*8 + 4 + (ln>>4))*128 + mw + (ln&15)))*8, &Aring[sl2][w][4][0][0]);
                asm volatile("s_waitcnt vmcnt(4)" ::: "memory");   // round r complete, 2 rounds in flight
            } else if (r == NR-2) {
                asm volatile("s_waitcnt vmcnt(2)" ::: "memory");
            } else {
                asm volatile("s_waitcnt vmcnt(0)" ::: "memory");
            }
            const int sl = r & 3;
            #pragma unroll
            for (int kk = 0; kk < 2; ++kk) {
                short8 af = *(const short8*)&Aring[sl][w][kk*4 + fq][fr][0];
                if (r < 16) {              // h_hi: vs Whh_hi AND Whh_lo
                    const int bs = r*8 + kk*4 + fq;
                    aH0 = __builtin_amdgcn_mfma_f32_16x16x32_bf16(af, *(const short8*)&Blds[bs][fr][0], aH0, 0, 0, 0);
                    aH1 = __builtin_amdgcn_mfma_f32_16x16x32_bf16(af, *(const short8*)&Blds[128 + bs][fr][0], aH1, 0, 0, 0);
                } else if (r < 32) {       // h_lo: vs Whh_hi
                    const int bs = (r-16)*8 + kk*4 + fq;
                    if (kk == 0) aH0 = __builtin_amdgcn_mfma_f32_16x16x32_bf16(af, *(const short8*)&Blds[bs][fr][0], aH0, 0, 0, 0);
                    else         aH1 = __builtin_amdgcn_mfma_f32_16x16x32_bf16(af, *(const short8*)&Blds[bs][fr][0], aH1, 0, 0, 0);
                } else if (r < 38) {       // e_hi: vs Wih_hi AND Wih_lo
                    const int bs = 256 + (r-32)*8 + kk*4 + fq;
                    aE0 = __builtin_amdgcn_mfma_f32_16x16x32_bf16(af, *(const short8*)&Blds[bs][fr][0], aE0, 0, 0, 0);
                    aE1 = __builtin_amdgcn_mfma_f32_16x16x32_bf16(af, *(const short8*)&Blds[48 + bs][fr][0], aE1, 0, 0, 0);
                } else {                   // e_lo: vs Wih_hi
                    const int bs = 256 + (r-38)*8 + kk*4 + fq;
                    if (kk == 0) aE0 = __builtin_amdgcn_mfma_f32_16x16x32_bf16(af, *(const short8*)&Blds[bs][fr][0], aE0, 0, 0, 0);
                    else         aE1 = __builtin_amdgcn_mfma_f32_16x16x32_bf16(af, *(const short8*)&Blds[bs][fr][0], aE1, 0, 0, 0);
                }
            }
        }

        // -------- block-local epilogue --------
        __syncthreads();
        float* Cex = (float*)&Aring[0][0][0][0][0];   // alias ring: [8 waves][2][16 rows][16 cols]
        {
            floatx4 accH = aH0 + aH1, accE = aE0 + aE1;
            #pragma unroll
            for (int reg = 0; reg < 4; ++reg) {
                Cex[((w*2 + 0)*16 + (fq*4 + reg))*16 + fr] = accH[reg];
                Cex[((w*2 + 1)*16 + (fq*4 + reg))*16 + fr] = accE[reg];
            }
        }
        __syncthreads();
        {
            const int b = tid >> 2, jl = tid & 3;
            const int wv = b >> 4, rowl = b & 15;
            float sr = Cex[((wv*2+0)*16 + rowl)*16 + jl]     + Cex[((wv*2+1)*16 + rowl)*16 + jl];
            float sz = Cex[((wv*2+0)*16 + rowl)*16 + 4 + jl] + Cex[((wv*2+1)*16 + rowl)*16 + 4 + jl];
            float hn = Cex[((wv*2+0)*16 + rowl)*16 + 8 + jl];
            float xn = Cex[((wv*2+1)*16 + rowl)*16 + 8 + jl];
            float rg = sigf(sr + lbias[jl][0]);
            float zg = sigf(sz + lbias[jl][1]);
            float ng = tanhf(xn + lbias[jl][3] + rg * (hn + lbias[jl][2]));
            float hold = hloc[b][jl];
            float hnew = lgate[jl] * ((1.f - zg) * ng + zg * hold);
            hloc[b][jl] = hnew;
            const int j = j0 + jl;
            unsigned short hi = bfhi(hnew);
            g_Abuf[par ^ 1][j>>3][b][j&7] = hi;
            g_Abuf[par ^ 1][128 + (j>>3)][b][j&7] = bfhi(hnew - bf2f(hi));
            if (t == T_-1) out[(size_t)b*H_ + j] = hnew;
        }
        // e-gather+split for t+1 into opposite parity (192 threads/block cover grid slice)
        if (t + 1 < T_ && tid < 192) {
            int idx = bid * 192 + tid;
            int b2 = idx / 384, jj = idx % 384;
            float v = (jj < E_) ? emb[(size_t)x[b2*T_ + t + 1]*E_ + jj] : 0.f;
            unsigned short hi = bfhi(v);
            g_Abuf[par ^ 1][256 + (jj>>3)][b2][jj&7] = hi;
            g_Abuf[par ^ 1][304 + (jj>>3)][b2][jj&7] = bfhi(v - bf2f(hi));
        }
        gbar(++bstep);   // ONE barrier per step (parity dbuf makes it sufficient)
    }
}

extern "C" void kernel_launch(void* const* d_in, const int* in_sizes, int n_in,
                              void* d_out, int out_size, void* d_ws, size_t ws_size,
                              hipStream_t stream) {
    const int*   x       = (const int*)d_in[0];
    const int*   key_ids = (const int*)d_in[1];
    const float* emb     = (const float*)d_in[2];
    const float* W_ih    = (const float*)d_in[3];
    const float* W_hh    = (const float*)d_in[4];
    const float* b_ih    = (const float*)d_in[5];
    const float* b_hh    = (const float*)d_in[6];
    const float* W_g     = (const float*)d_in[7];
    const float* b_g     = (const float*)d_in[8];
    float* out = (float*)d_out;

    void* args[] = {(void*)&x, (void*)&key_ids, (void*)&emb, (void*)&W_ih, (void*)&W_hh,
                    (void*)&b_ih, (void*)&b_hh, (void*)&W_g, (void*)&b_g, (void*)&out};
    hipLaunchCooperativeKernel((const void*)keyed_gru_kernel,
                               dim3(NBLK), dim3(NTHR), args, 0, stream);
}

// Round 9
// 15414.778 us; speedup vs baseline: 8.0280x; 1.2261x over previous
//
#include <hip/hip_runtime.h>

#define B_   128
#define T_   512
#define E_   300
#define H_   1024
#define KL_  15
#define G3_  3072

#define NBLK 256
#define NTHR 512
#define GT   (NBLK*NTHR)        // 131072 threads
#define NWAVE_G (GT/64)

// A-buf col-seg regions (per parity): [0,128) h_hi | [128,256) h_lo | [256,304) e_hi | [304,352) e_lo
#define ASEG 352
#define NR   44                 // staging rounds of 8 col-segs (NR*8 == ASEG)

typedef __attribute__((ext_vector_type(8))) short short8;
typedef __attribute__((ext_vector_type(4))) float floatx4;

__device__ __align__(16) unsigned short g_Abuf[2][ASEG][B_][8];  // 2 x 704KB, parity-double-buffered
__device__ float g_keyxp[KL_][G3_];
__device__ float g_kh[2][H_];
__device__ float g_gate[H_];

// ---- barrier state: generation-based, persists across launches (zero-init BSS) ----
__device__ unsigned g_abar[NBLK];
__device__ unsigned g_gen;

// heavy barrier: RELEASE slot store (s_waitcnt + buffer_wbl2 -> flushes cached Phase-0
// writes to the coherence point). Used exactly once, after Phase 0.
// Centralized: block 0 gathers slots, broadcasts g_gen; exit implies observed g_gen.
__device__ __forceinline__ void gbar_heavy(unsigned step) {
    const int tid = threadIdx.x, bid = blockIdx.x;
    __syncthreads();
    if (tid == 0)
        __hip_atomic_store(&g_abar[bid], step, __ATOMIC_RELEASE, __HIP_MEMORY_SCOPE_AGENT);
    if (bid == 0) {
        if (tid < NBLK) {
            while (__hip_atomic_load(&g_abar[tid], __ATOMIC_RELAXED, __HIP_MEMORY_SCOPE_AGENT) < step)
                __builtin_amdgcn_s_sleep(2);
        }
        __syncthreads();
        if (tid == 0)
            __hip_atomic_store(&g_gen, step, __ATOMIC_RELEASE, __HIP_MEMORY_SCOPE_AGENT);
    } else {
        if (tid == 0) {
            while (__hip_atomic_load(&g_gen, __ATOMIC_RELAXED, __HIP_MEMORY_SCOPE_AGENT) < step)
                __builtin_amdgcn_s_sleep(2);
        }
    }
    if (tid == 0)
        (void)__hip_atomic_load(&g_gen, __ATOMIC_ACQUIRE, __HIP_MEMORY_SCOPE_AGENT);  // buffer_inv
    __syncthreads();
}

// light barrier: NO wbl2. Cross-block data is written with agent-scope (sc1) stores that
// land at L3; __syncthreads' vmcnt(0) drain makes them globally visible before the slot
// store. Centralized g_gen broadcast (exit implies observed g_gen -> cross-launch safe);
// one buffer_inv per block on exit so cached reads refetch L3.
__device__ __forceinline__ void gbar_light(unsigned step) {
    const int tid = threadIdx.x, bid = blockIdx.x;
    __syncthreads();   // vmcnt(0): all sc1 data stores acked at coherence point
    if (tid == 0)
        __hip_atomic_store(&g_abar[bid], step, __ATOMIC_RELAXED, __HIP_MEMORY_SCOPE_AGENT);
    if (bid == 0) {
        if (tid < NBLK) {
            while (__hip_atomic_load(&g_abar[tid], __ATOMIC_RELAXED, __HIP_MEMORY_SCOPE_AGENT) < step)
                __builtin_amdgcn_s_sleep(2);
        }
        __syncthreads();
        if (tid == 0)
            __hip_atomic_store(&g_gen, step, __ATOMIC_RELAXED, __HIP_MEMORY_SCOPE_AGENT);
    } else {
        if (tid == 0) {
            while (__hip_atomic_load(&g_gen, __ATOMIC_RELAXED, __HIP_MEMORY_SCOPE_AGENT) < step)
                __builtin_amdgcn_s_sleep(2);
        }
    }
    if (tid == 0)
        (void)__hip_atomic_load(&g_gen, __ATOMIC_ACQUIRE, __HIP_MEMORY_SCOPE_AGENT);  // buffer_inv
    __syncthreads();
}

__device__ __forceinline__ float sigf(float v){ return 1.0f/(1.0f+expf(-v)); }
__device__ __forceinline__ unsigned short bfhi(float f){
    unsigned u = __float_as_uint(f);
    return (unsigned short)((u + 0x7FFFu + ((u>>16)&1u)) >> 16);
}
__device__ __forceinline__ float bf2f(unsigned short h){ return __uint_as_float(((unsigned)h)<<16); }

__device__ __forceinline__ void st_agent_u16(unsigned short* p, unsigned short v){
    __hip_atomic_store(p, v, __ATOMIC_RELAXED, __HIP_MEMORY_SCOPE_AGENT);
}
__device__ __forceinline__ void st_agent_f32(float* p, float v){
    __hip_atomic_store(p, v, __ATOMIC_RELAXED, __HIP_MEMORY_SCOPE_AGENT);
}

#define GLOAD_LDS16(g, l) __builtin_amdgcn_global_load_lds( \
    (const __attribute__((address_space(1))) unsigned int*)(g), \
    (__attribute__((address_space(3))) unsigned int*)(l), 16, 0, 0)

__global__ void __launch_bounds__(NTHR, 1) keyed_gru_kernel(
    const int* __restrict__ x, const int* __restrict__ key_ids,
    const float* __restrict__ emb, const float* __restrict__ W_ih,
    const float* __restrict__ W_hh, const float* __restrict__ b_ih,
    const float* __restrict__ b_hh, const float* __restrict__ W_g,
    const float* __restrict__ b_g, float* __restrict__ out)
{
    const int tid  = threadIdx.x;
    const int bid  = blockIdx.x;
    const int gtid = bid * NTHR + tid;

    unsigned bstep = __hip_atomic_load(&g_gen, __ATOMIC_RELAXED, __HIP_MEMORY_SCOPE_AGENT);

    __shared__ __align__(16) unsigned short Blds[ASEG][16][8];      // 90112 B
    __shared__ __align__(16) unsigned short Aring[4][8][8][16][8];  // 65536 B
    __shared__ float hloc[B_][4];
    __shared__ float lbias[4][4];
    __shared__ float lgate[4];

    const int j0 = bid * 4;       // block's 4 h-channels

    // ---------------- Phase 0 (plain cached stores; flushed by gbar_heavy) ----------------
    for (int idx = gtid; idx < 2*ASEG*B_*8; idx += GT)
        ((unsigned short*)g_Abuf)[idx] = 0;
    for (int idx = gtid; idx < B_*384; idx += GT) {
        int b = idx / 384, jj = idx % 384;
        float v = (jj < E_) ? emb[(size_t)x[b*T_ + 0]*E_ + jj] : 0.f;
        unsigned short hi = bfhi(v);
        g_Abuf[0][256 + (jj>>3)][b][jj&7] = hi;
        g_Abuf[0][304 + (jj>>3)][b][jj&7] = bfhi(v - bf2f(hi));
    }
    for (int idx = gtid; idx < KL_*G3_; idx += GT) {
        int s = idx / G3_, g = idx - s*G3_;
        const float* e = emb + (size_t)key_ids[s]*E_;
        const float* wv = W_ih + (size_t)g*E_;
        float acc = b_ih[g];
        for (int k = 0; k < E_; ++k) acc = fmaf(e[k], wv[k], acc);
        g_keyxp[s][g] = acc;
    }
    if (gtid < H_) g_kh[0][gtid] = 0.f;
    for (int idx = tid; idx < ASEG*16; idx += NTHR) {
        int seg = idx >> 4, c = idx & 15;
        unsigned short v[8];
        if (c >= 12) {
            #pragma unroll
            for (int e2 = 0; e2 < 8; ++e2) v[e2] = 0;
        } else {
            int wr = (c < 4) ? (j0 + c) : (c < 8) ? (H_ + j0 + c - 4) : (2*H_ + j0 + c - 8);
            if (seg < 128) {                              // Whh_hi
                const float* src = W_hh + (size_t)wr*H_ + seg*8;
                #pragma unroll
                for (int e2 = 0; e2 < 8; ++e2) v[e2] = bfhi(src[e2]);
            } else if (seg < 256) {                       // Whh_lo
                const float* src = W_hh + (size_t)wr*H_ + (seg-128)*8;
                #pragma unroll
                for (int e2 = 0; e2 < 8; ++e2) { unsigned short hi = bfhi(src[e2]); v[e2] = bfhi(src[e2] - bf2f(hi)); }
            } else if (seg < 304) {                       // Wih_hi (k padded 300->384)
                int k0 = (seg-256)*8;
                #pragma unroll
                for (int e2 = 0; e2 < 8; ++e2) { int k = k0+e2; v[e2] = (k < E_) ? bfhi(W_ih[(size_t)wr*E_ + k]) : (unsigned short)0; }
            } else {                                      // Wih_lo
                int k0 = (seg-304)*8;
                #pragma unroll
                for (int e2 = 0; e2 < 8; ++e2) {
                    int k = k0+e2;
                    if (k < E_) { float f = W_ih[(size_t)wr*E_ + k]; unsigned short hi = bfhi(f); v[e2] = bfhi(f - bf2f(hi)); }
                    else v[e2] = 0;
                }
            }
        }
        #pragma unroll
        for (int e2 = 0; e2 < 8; ++e2) Blds[seg][c][e2] = v[e2];
    }
    hloc[tid >> 2][tid & 3] = 0.f;
    gbar_heavy(++bstep);           // flush all cached Phase-0 writes (wbl2) + inv

    // ---------------- Phase 1: key GRU (15 steps, fp32) ----------------
    const int wid0 = gtid >> 6;
    const int lane = tid & 63;
    int cur = 0;
    for (int t = 0; t < KL_; ++t) {
        for (int j = wid0; j < H_; j += NWAVE_G) {
            const float* wr = W_hh + (size_t)j * H_;
            const float* wz = W_hh + (size_t)(j + H_) * H_;
            const float* wn = W_hh + (size_t)(j + 2*H_) * H_;
            float ar = 0.f, az = 0.f, an = 0.f;
            for (int k = lane; k < H_; k += 64) {
                float hv = g_kh[cur][k];
                ar = fmaf(hv, wr[k], ar); az = fmaf(hv, wz[k], az); an = fmaf(hv, wn[k], an);
            }
            #pragma unroll
            for (int off = 32; off > 0; off >>= 1) {
                ar += __shfl_down(ar, off); az += __shfl_down(az, off); an += __shfl_down(an, off);
            }
            if (lane == 0) {
                float r = sigf(g_keyxp[t][j] + ar + b_hh[j]);
                float z = sigf(g_keyxp[t][j + H_] + az + b_hh[j + H_]);
                float n = tanhf(g_keyxp[t][j + 2*H_] + r * (an + b_hh[j + 2*H_]));
                st_agent_f32(&g_kh[cur ^ 1][j], (1.f - z) * n + z * g_kh[cur][j]);
            }
        }
        gbar_light(++bstep);
        cur ^= 1;
    }
    // ---------------- Phase 2: key gate ----------------
    for (int j = wid0; j < H_; j += NWAVE_G) {
        const float* wg = W_g + (size_t)j * H_;
        float a = 0.f;
        for (int k = lane; k < H_; k += 64) a = fmaf(g_kh[cur][k], wg[k], a);
        #pragma unroll
        for (int off = 32; off > 0; off >>= 1) a += __shfl_down(a, off);
        if (lane == 0) st_agent_f32(&g_gate[j], sigf(a + b_g[j]));
    }
    gbar_light(++bstep);

    if (tid < 4) {
        int j = j0 + tid;
        lgate[tid]    = g_gate[j];
        lbias[tid][0] = b_ih[j] + b_hh[j];
        lbias[tid][1] = b_ih[H_+j] + b_hh[H_+j];
        lbias[tid][2] = b_hh[2*H_+j];
        lbias[tid][3] = b_ih[2*H_+j];
    }
    __syncthreads();

    // ---------------- Phase 3: main recurrence ----------------
    const int w  = tid >> 6;        // wave 0..7 owns batch rows [16w,16w+16)
    const int ln = tid & 63;
    const int mw = w * 16;
    const int fr = ln & 15;
    const int fq = ln >> 4;

    for (int t = 0; t < T_; ++t) {
        const int par = t & 1;
        const unsigned short* Ab = &g_Abuf[par][0][0][0];

        floatx4 aH0 = {0,0,0,0}, aH1 = {0,0,0,0}, aE0 = {0,0,0,0}, aE1 = {0,0,0,0};

        // prologue: prefetch rounds 0,1,2 (per-wave private; DIRECT col-seg addressing)
        #pragma unroll
        for (int pr = 0; pr < 3; ++pr) {
            GLOAD_LDS16(Ab + ((size_t)((pr*8     + (ln>>4))*128 + mw + (ln&15)))*8, &Aring[pr][w][0][0][0]);
            GLOAD_LDS16(Ab + ((size_t)((pr*8 + 4 + (ln>>4))*128 + mw + (ln&15)))*8, &Aring[pr][w][4][0][0]);
        }

        for (int r = 0; r < NR; ++r) {
            if (r < NR-3) {
                const int rr = r + 3, sl2 = rr & 3;
                GLOAD_LDS16(Ab + ((size_t)((rr*8     + (ln>>4))*128 + mw + (ln&15)))*8, &Aring[sl2][w][0][0][0]);
                GLOAD_LDS16(Ab + ((size_t)((rr*8 + 4 + (ln>>4))*128 + mw + (ln&15)))*8, &Aring[sl2][w][4][0][0]);
                asm volatile("s_waitcnt vmcnt(6)" ::: "memory");
            } else if (r == NR-3) {
                asm volatile("s_waitcnt vmcnt(4)" ::: "memory");
            } else if (r == NR-2) {
                asm volatile("s_waitcnt vmcnt(2)" ::: "memory");
            } else {
                asm volatile("s_waitcnt vmcnt(0)" ::: "memory");
            }
            const int sl = r & 3;
            #pragma unroll
            for (int kk = 0; kk < 2; ++kk) {
                short8 af = *(const short8*)&Aring[sl][w][kk*4 + fq][fr][0];
                if (r < 16) {              // h_hi: vs Whh_hi AND Whh_lo
                    const int bs = r*8 + kk*4 + fq;
                    aH0 = __builtin_amdgcn_mfma_f32_16x16x32_bf16(af, *(const short8*)&Blds[bs][fr][0], aH0, 0, 0, 0);
                    aH1 = __builtin_amdgcn_mfma_f32_16x16x32_bf16(af, *(const short8*)&Blds[128 + bs][fr][0], aH1, 0, 0, 0);
                } else if (r < 32) {       // h_lo: vs Whh_hi
                    const int bs = (r-16)*8 + kk*4 + fq;
                    if (kk == 0) aH0 = __builtin_amdgcn_mfma_f32_16x16x32_bf16(af, *(const short8*)&Blds[bs][fr][0], aH0, 0, 0, 0);
                    else         aH1 = __builtin_amdgcn_mfma_f32_16x16x32_bf16(af, *(const short8*)&Blds[bs][fr][0], aH1, 0, 0, 0);
                } else if (r < 38) {       // e_hi: vs Wih_hi AND Wih_lo
                    const int bs = 256 + (r-32)*8 + kk*4 + fq;
                    aE0 = __builtin_amdgcn_mfma_f32_16x16x32_bf16(af, *(const short8*)&Blds[bs][fr][0], aE0, 0, 0, 0);
                    aE1 = __builtin_amdgcn_mfma_f32_16x16x32_bf16(af, *(const short8*)&Blds[48 + bs][fr][0], aE1, 0, 0, 0);
                } else {                   // e_lo: vs Wih_hi
                    const int bs = 256 + (r-38)*8 + kk*4 + fq;
                    if (kk == 0) aE0 = __builtin_amdgcn_mfma_f32_16x16x32_bf16(af, *(const short8*)&Blds[bs][fr][0], aE0, 0, 0, 0);
                    else         aE1 = __builtin_amdgcn_mfma_f32_16x16x32_bf16(af, *(const short8*)&Blds[bs][fr][0], aE1, 0, 0, 0);
                }
            }
        }

        // -------- block-local epilogue --------
        __syncthreads();
        float* Cex = (float*)&Aring[0][0][0][0][0];   // alias ring: [8 waves][2][16 rows][16 cols]
        {
            floatx4 accH = aH0 + aH1, accE = aE0 + aE1;
            #pragma unroll
            for (int reg = 0; reg < 4; ++reg) {
                Cex[((w*2 + 0)*16 + (fq*4 + reg))*16 + fr] = accH[reg];
                Cex[((w*2 + 1)*16 + (fq*4 + reg))*16 + fr] = accE[reg];
            }
        }
        __syncthreads();
        {
            const int b = tid >> 2, jl = tid & 3;
            const int wv = b >> 4, rowl = b & 15;
            float sr = Cex[((wv*2+0)*16 + rowl)*16 + jl]     + Cex[((wv*2+1)*16 + rowl)*16 + jl];
            float sz = Cex[((wv*2+0)*16 + rowl)*16 + 4 + jl] + Cex[((wv*2+1)*16 + rowl)*16 + 4 + jl];
            float hn = Cex[((wv*2+0)*16 + rowl)*16 + 8 + jl];
            float xn = Cex[((wv*2+1)*16 + rowl)*16 + 8 + jl];
            float rg = sigf(sr + lbias[jl][0]);
            float zg = sigf(sz + lbias[jl][1]);
            float ng = tanhf(xn + lbias[jl][3] + rg * (hn + lbias[jl][2]));
            float hold = hloc[b][jl];
            float hnew = lgate[jl] * ((1.f - zg) * ng + zg * hold);
            hloc[b][jl] = hnew;
            const int j = j0 + jl;
            unsigned short hi = bfhi(hnew);
            st_agent_u16(&g_Abuf[par ^ 1][j>>3][b][j&7], hi);
            st_agent_u16(&g_Abuf[par ^ 1][128 + (j>>3)][b][j&7], bfhi(hnew - bf2f(hi)));
            if (t == T_-1) st_agent_f32(&out[(size_t)b*H_ + j], hnew);
        }
        // e-gather+split for t+1 into opposite parity
        if (t + 1 < T_ && tid < 192) {
            int idx = bid * 192 + tid;
            int b2 = idx / 384, jj = idx % 384;
            float v = (jj < E_) ? emb[(size_t)x[b2*T_ + t + 1]*E_ + jj] : 0.f;
            unsigned short hi = bfhi(v);
            st_agent_u16(&g_Abuf[par ^ 1][256 + (jj>>3)][b2][jj&7], hi);
            st_agent_u16(&g_Abuf[par ^ 1][304 + (jj>>3)][b2][jj&7], bfhi(v - bf2f(hi)));
        }
        gbar_light(++bstep);   // no wbl2; centralized g_gen; one buffer_inv per block
    }
}

extern "C" void kernel_launch(void* const* d_in, const int* in_sizes, int n_in,
                              void* d_out, int out_size, void* d_ws, size_t ws_size,
                              hipStream_t stream) {
    const int*   x       = (const int*)d_in[0];
    const int*   key_ids = (const int*)d_in[1];
    const float* emb     = (const float*)d_in[2];
    const float* W_ih    = (const float*)d_in[3];
    const float* W_hh    = (const float*)d_in[4];
    const float* b_ih    = (const float*)d_in[5];
    const float* b_hh    = (const float*)d_in[6];
    const float* W_g     = (const float*)d_in[7];
    const float* b_g     = (const float*)d_in[8];
    float* out = (float*)d_out;

    void* args[] = {(void*)&x, (void*)&key_ids, (void*)&emb, (void*)&W_ih, (void*)&W_hh,
                    (void*)&b_ih, (void*)&b_hh, (void*)&W_g, (void*)&b_g, (void*)&out};
    hipLaunchCooperativeKernel((const void*)keyed_gru_kernel,
                               dim3(NBLK), dim3(NTHR), args, 0, stream);
}